// Round 1
// baseline (431.744 us; speedup 1.0000x reference)
//
#include <hip/hip_runtime.h>
#include <math.h>

// GATv2 x2 layers, N=50000 nodes, E=600000 edges, D=128.
// Structure per call:
//   1. CSR build over dst (with self loops): counts -> scan -> scatter.  (dst fixed across layers)
//   2. Per layer: fused GEMM (xl = h@Wl+bl, xr = h@Wr+br, res = h@W_res+b_res),
//      then per-node online-softmax aggregation (1 wave / node).
// All fp32 (no fp32 MFMA on CDNA4; vector-ALU tiled GEMM).

#define DIM 128
#define NEG_SLOPE 0.2f
#define BM 64
#define BK 32

__global__ void k_init_counts(int* __restrict__ counts, int n) {
    int i = blockIdx.x * blockDim.x + threadIdx.x;
    if (i < n) counts[i] = 1;  // self loop
}

__global__ void k_count(const int* __restrict__ dst, int E, int* __restrict__ counts) {
    int k = blockIdx.x * blockDim.x + threadIdx.x;
    if (k < E) atomicAdd(&counts[dst[k]], 1);
}

// inclusive scan of counts within 256-blocks -> rowptr[i+1], block totals -> bsum
__global__ void k_scan1(const int* __restrict__ counts, int n,
                        int* __restrict__ rowptr, int* __restrict__ bsum) {
    __shared__ int s[256];
    int tid = threadIdx.x;
    int i = blockIdx.x * 256 + tid;
    int v = (i < n) ? counts[i] : 0;
    s[tid] = v;
    __syncthreads();
    for (int off = 1; off < 256; off <<= 1) {
        int t = (tid >= off) ? s[tid - off] : 0;
        __syncthreads();
        s[tid] += t;
        __syncthreads();
    }
    if (i < n) rowptr[i + 1] = s[tid];
    if (tid == 255) bsum[blockIdx.x] = s[255];
}

// single-block inclusive scan of block sums (nb <= 256)
__global__ void k_scan2(int* __restrict__ bsum, int nb) {
    __shared__ int s[256];
    int tid = threadIdx.x;
    int v = (tid < nb) ? bsum[tid] : 0;
    s[tid] = v;
    __syncthreads();
    for (int off = 1; off < 256; off <<= 1) {
        int t = (tid >= off) ? s[tid - off] : 0;
        __syncthreads();
        s[tid] += t;
        __syncthreads();
    }
    if (tid < nb) bsum[tid] = s[tid];
}

// add block offsets -> global inclusive in rowptr[i+1]; rowptr[0]=0;
// cursors[i] = exclusive prefix = inclusive - counts[i]  (counts read from same buffer)
__global__ void k_scan3(int* __restrict__ rowptr, const int* __restrict__ bsum,
                        int n, int* __restrict__ counts_to_cursors) {
    int i = blockIdx.x * 256 + threadIdx.x;
    if (i < n) {
        int add = (blockIdx.x > 0) ? bsum[blockIdx.x - 1] : 0;
        int cnt = counts_to_cursors[i];
        int v = rowptr[i + 1] + add;
        rowptr[i + 1] = v;
        counts_to_cursors[i] = v - cnt;  // start offset (cursor)
    }
    if (i == 0) rowptr[0] = 0;
}

__global__ void k_scatter(const int* __restrict__ src, const int* __restrict__ dst,
                          int E, int n, int* __restrict__ cur, int* __restrict__ srt) {
    int k = blockIdx.x * blockDim.x + threadIdx.x;
    int tot = E + n;
    if (k >= tot) return;
    int s, d;
    if (k < E) { s = src[k]; d = dst[k]; }
    else       { s = k - E;  d = s; }       // self loops appended
    int p = atomicAdd(&cur[d], 1);
    srt[p] = s;
}

// C_sec = H @ W_sec + b_sec for sec in {Wl->XL, Wr->XR, Wres->RES}; BN = DIM = 128.
__global__ __launch_bounds__(256) void k_gemm(
    const float* __restrict__ H,
    const float* __restrict__ Wl, const float* __restrict__ Wr, const float* __restrict__ Wres,
    const float* __restrict__ bl, const float* __restrict__ br, const float* __restrict__ bres,
    float* __restrict__ XL, float* __restrict__ XR, float* __restrict__ RES, int n)
{
    int sec = blockIdx.y;
    const float* W    = (sec == 0) ? Wl : ((sec == 1) ? Wr : Wres);
    const float* bias = (sec == 0) ? bl : ((sec == 1) ? br : bres);
    float* C          = (sec == 0) ? XL : ((sec == 1) ? XR : RES);
    int row0 = blockIdx.x * BM;

    __shared__ float As[BM][BK + 1];
    __shared__ float Bs[BK][DIM];

    int tid = threadIdx.x;
    int ty = tid >> 4;   // 0..15 -> rows ty*4..ty*4+3
    int tx = tid & 15;   // cols tx + 16*j

    float acc[4][8];
#pragma unroll
    for (int i = 0; i < 4; i++)
#pragma unroll
        for (int j = 0; j < 8; j++) acc[i][j] = 0.f;

    for (int k0 = 0; k0 < DIM; k0 += BK) {
        // A tile: 64x32 floats = 512 float4, 2 per thread
#pragma unroll
        for (int t = 0; t < 2; t++) {
            int idx = tid + t * 256;      // 0..511
            int r = idx >> 3;
            int c4 = (idx & 7) << 2;
            float4 v;
            int gr = row0 + r;
            if (gr < n) v = *(const float4*)(H + (size_t)gr * DIM + k0 + c4);
            else        v = make_float4(0.f, 0.f, 0.f, 0.f);
            As[r][c4 + 0] = v.x; As[r][c4 + 1] = v.y;
            As[r][c4 + 2] = v.z; As[r][c4 + 3] = v.w;
        }
        // B tile: 32x128 floats = 1024 float4, 4 per thread
#pragma unroll
        for (int t = 0; t < 4; t++) {
            int idx = tid + t * 256;      // 0..1023
            int r = idx >> 5;
            int c4 = (idx & 31) << 2;
            float4 v = *(const float4*)(W + (size_t)(k0 + r) * DIM + c4);
            *(float4*)(&Bs[r][c4]) = v;
        }
        __syncthreads();
#pragma unroll
        for (int kk = 0; kk < BK; kk++) {
            float a[4], b[8];
#pragma unroll
            for (int i = 0; i < 4; i++) a[i] = As[ty * 4 + i][kk];
#pragma unroll
            for (int j = 0; j < 8; j++) b[j] = Bs[kk][tx + 16 * j];
#pragma unroll
            for (int i = 0; i < 4; i++)
#pragma unroll
                for (int j = 0; j < 8; j++) acc[i][j] += a[i] * b[j];
        }
        __syncthreads();
    }
#pragma unroll
    for (int i = 0; i < 4; i++) {
        int gr = row0 + ty * 4 + i;
        if (gr >= n) continue;
#pragma unroll
        for (int j = 0; j < 8; j++) {
            int c = tx + 16 * j;
            C[(size_t)gr * DIM + c] = acc[i][j] + bias[c];
        }
    }
}

// One wave (64 lanes) per destination node; online softmax over its CSR edge list.
// lane handles dims {2*lane, 2*lane+1} (float2 -> 512B coalesced per edge row).
__global__ __launch_bounds__(256) void k_aggr(
    const float* __restrict__ XL, const float* __restrict__ XR, const float* __restrict__ RES,
    const float* __restrict__ att, const float* __restrict__ bias,
    const int* __restrict__ rowptr, const int* __restrict__ srt,
    float* __restrict__ out, int n)
{
    int wave = threadIdx.x >> 6;
    int lane = threadIdx.x & 63;
    int node = blockIdx.x * 4 + wave;
    if (node >= n) return;

    float2 a2  = *(const float2*)(att + 2 * lane);
    float2 xr2 = *(const float2*)(XR + (size_t)node * DIM + 2 * lane);
    int beg = rowptr[node], end = rowptr[node + 1];

    float m = -INFINITY, den = 0.f;
    float2 acc = make_float2(0.f, 0.f);

    for (int j = beg; j < end; j++) {
        int s = srt[j];
        float2 v = *(const float2*)(XL + (size_t)s * DIM + 2 * lane);
        float tx0 = v.x + xr2.x, ty0 = v.y + xr2.y;
        float lx = tx0 > 0.f ? tx0 : NEG_SLOPE * tx0;
        float ly = ty0 > 0.f ? ty0 : NEG_SLOPE * ty0;
        float p = lx * a2.x + ly * a2.y;
#pragma unroll
        for (int off = 32; off >= 1; off >>= 1) p += __shfl_xor(p, off);
        float mn = fmaxf(m, p);
        float c = __expf(m - mn);   // first iter: exp(-inf) = 0
        float w = __expf(p - mn);
        acc.x = acc.x * c + w * v.x;
        acc.y = acc.y * c + w * v.y;
        den = den * c + w;
        m = mn;
    }

    float2 r2 = *(const float2*)(RES + (size_t)node * DIM + 2 * lane);
    float2 b2 = *(const float2*)(bias + 2 * lane);
    float inv = 1.f / (den + 1e-16f);
    float ox = fmaxf(acc.x * inv + b2.x + r2.x, 0.f);
    float oy = fmaxf(acc.y * inv + b2.y + r2.y, 0.f);
    *(float2*)(out + (size_t)node * DIM + 2 * lane) = make_float2(ox, oy);
}

extern "C" void kernel_launch(void* const* d_in, const int* in_sizes, int n_in,
                              void* d_out, int out_size, void* d_ws, size_t ws_size,
                              hipStream_t stream) {
    const float* x    = (const float*)d_in[0];
    const int*   ei   = (const int*)d_in[1];
    const float* Wl   = (const float*)d_in[2];
    const float* bl   = (const float*)d_in[3];
    const float* Wr   = (const float*)d_in[4];
    const float* br   = (const float*)d_in[5];
    const float* att  = (const float*)d_in[6];
    const float* bias = (const float*)d_in[7];
    const float* Wres = (const float*)d_in[8];
    const float* bres = (const float*)d_in[9];

    int n = in_sizes[0] / DIM;
    int E = in_sizes[1] / 2;
    const int* srcIdx = ei;       // edge_index[0]
    const int* dstIdx = ei + E;   // edge_index[1]

    // workspace layout (floats then ints)
    float* xl   = (float*)d_ws;
    float* xr   = xl + (size_t)n * DIM;
    float* resb = xr + (size_t)n * DIM;
    float* hbuf = resb + (size_t)n * DIM;
    int* rowptr = (int*)(hbuf + (size_t)n * DIM);
    int* tmpc   = rowptr + (n + 1);
    int* srt    = tmpc + n;
    int* bsum   = srt + (E + n);

    int nb1 = (n + 255) / 256;

    k_init_counts<<<(n + 255) / 256, 256, 0, stream>>>(tmpc, n);
    k_count<<<(E + 255) / 256, 256, 0, stream>>>(dstIdx, E, tmpc);
    k_scan1<<<nb1, 256, 0, stream>>>(tmpc, n, rowptr, bsum);
    k_scan2<<<1, 256, 0, stream>>>(bsum, nb1);
    k_scan3<<<nb1, 256, 0, stream>>>(rowptr, bsum, n, tmpc);
    k_scatter<<<(E + n + 255) / 256, 256, 0, stream>>>(srcIdx, dstIdx, E, n, tmpc, srt);

    const float* h = x;
    for (int l = 0; l < 2; l++) {
        float* ho = (l == 0) ? hbuf : (float*)d_out;
        dim3 g((n + BM - 1) / BM, 3);
        k_gemm<<<g, 256, 0, stream>>>(h, Wl + (size_t)l * DIM * DIM, Wr + (size_t)l * DIM * DIM, Wres,
                                      bl + (size_t)l * DIM, br + (size_t)l * DIM, bres,
                                      xl, xr, resb, n);
        k_aggr<<<(n + 3) / 4, 256, 0, stream>>>(xl, xr, resb, att + (size_t)l * DIM,
                                                bias + (size_t)l * DIM, rowptr, srt, ho, n);
        h = ho;
    }
}

// Round 2
// 258.772 us; speedup vs baseline: 1.6684x; 1.6684x over previous
//
#include <hip/hip_runtime.h>
#include <math.h>

// GATv2 x2 layers, N=50000, E=600000, D=128.
//  1. CSR over dst (self loops included): counts -> scan -> scatter.
//  2. Per layer: bf16-MFMA fused GEMM (XL bf16, XR fp32, RES fp32), then
//     per-node online-softmax aggregation (1 wave / node, 2 half-wave subgroups).

#define DIM 128
#define NEG_SLOPE 0.2f

typedef __attribute__((ext_vector_type(8))) short short8;
typedef __attribute__((ext_vector_type(4))) float floatx4;

static __device__ __forceinline__ unsigned short f2b(float f) {
    unsigned u = __float_as_uint(f);
    unsigned r = (u + 0x7FFFu + ((u >> 16) & 1u)) >> 16;   // RNE
    return (unsigned short)r;
}
static __device__ __forceinline__ float b2f(unsigned short h) {
    return __uint_as_float(((unsigned)h) << 16);
}

// ---------------- CSR build ----------------
__global__ void k_init_counts(int* __restrict__ counts, int n) {
    int i = blockIdx.x * blockDim.x + threadIdx.x;
    if (i < n) counts[i] = 1;  // self loop
}

__global__ void k_count(const int* __restrict__ dst, int E, int* __restrict__ counts) {
    int k = blockIdx.x * blockDim.x + threadIdx.x;
    if (k < E) atomicAdd(&counts[dst[k]], 1);
}

__global__ void k_scan1(const int* __restrict__ counts, int n,
                        int* __restrict__ rowptr, int* __restrict__ bsum) {
    __shared__ int s[256];
    int tid = threadIdx.x;
    int i = blockIdx.x * 256 + tid;
    int v = (i < n) ? counts[i] : 0;
    s[tid] = v;
    __syncthreads();
    for (int off = 1; off < 256; off <<= 1) {
        int t = (tid >= off) ? s[tid - off] : 0;
        __syncthreads();
        s[tid] += t;
        __syncthreads();
    }
    if (i < n) rowptr[i + 1] = s[tid];
    if (tid == 255) bsum[blockIdx.x] = s[255];
}

__global__ void k_scan2(int* __restrict__ bsum, int nb) {
    __shared__ int s[256];
    int tid = threadIdx.x;
    int v = (tid < nb) ? bsum[tid] : 0;
    s[tid] = v;
    __syncthreads();
    for (int off = 1; off < 256; off <<= 1) {
        int t = (tid >= off) ? s[tid - off] : 0;
        __syncthreads();
        s[tid] += t;
        __syncthreads();
    }
    if (tid < nb) bsum[tid] = s[tid];
}

__global__ void k_scan3(int* __restrict__ rowptr, const int* __restrict__ bsum,
                        int n, int* __restrict__ counts_to_cursors) {
    int i = blockIdx.x * 256 + threadIdx.x;
    if (i < n) {
        int add = (blockIdx.x > 0) ? bsum[blockIdx.x - 1] : 0;
        int cnt = counts_to_cursors[i];
        int v = rowptr[i + 1] + add;
        rowptr[i + 1] = v;
        counts_to_cursors[i] = v - cnt;  // cursor = exclusive prefix
    }
    if (i == 0) rowptr[0] = 0;
}

__global__ void k_scatter(const int* __restrict__ src, const int* __restrict__ dst,
                          int E, int n, int* __restrict__ cur, int* __restrict__ srt) {
    int k = blockIdx.x * blockDim.x + threadIdx.x;
    int tot = E + n;
    if (k >= tot) return;
    int s, d;
    if (k < E) { s = src[k]; d = dst[k]; }
    else       { s = k - E;  d = s; }
    int p = atomicAdd(&cur[d], 1);
    srt[p] = s;
}

// ---------------- W pre-transpose+convert: Wt[l][sec][n][k] = bf16(W[k][n]) ----------------
__global__ void k_wconv(const float* __restrict__ Wl, const float* __restrict__ Wr,
                        const float* __restrict__ Wres, unsigned short* __restrict__ Wt) {
    int idx = blockIdx.x * blockDim.x + threadIdx.x;
    if (idx >= 2 * 3 * DIM * DIM) return;
    int k  = idx & 127;
    int nn = (idx >> 7) & 127;
    int v  = idx >> 14;            // 0..5 = l*3+sec
    int sec = v % 3, l = v / 3;
    const float* W = (sec == 0) ? (Wl + l * DIM * DIM)
                   : (sec == 1) ? (Wr + l * DIM * DIM) : Wres;
    Wt[idx] = f2b(W[k * DIM + nn]);
}

// ---------------- fused 3-section bf16 MFMA GEMM ----------------
// 512 threads (8 waves), BM=128 rows, K=N=128. LDS: A 128x136 + B 3x128x136 bf16.
__global__ __launch_bounds__(512) void k_gemm(
    const float* __restrict__ H, const unsigned short* __restrict__ Wt,
    const float* __restrict__ bl, const float* __restrict__ br, const float* __restrict__ bres,
    unsigned short* __restrict__ XLb, float* __restrict__ XR, float* __restrict__ RES, int n)
{
    __shared__ unsigned short As[128][136];
    __shared__ unsigned short Bs[3][128][136];
    int tid = threadIdx.x;
    int row0 = blockIdx.x * 128;

    // stage B (bf16, pre-transposed): 3*128*32 ushort4 chunks / 512 thr = 24 each
#pragma unroll
    for (int t = 0; t < 24; t++) {
        int c = tid + t * 512;
        int sec = c >> 12;
        int rem = c & 4095;
        int nn = rem >> 5;
        int k4 = (rem & 31) << 2;
        ushort4 v = *(const ushort4*)(Wt + ((sec * 128 + nn) << 7) + k4);
        *(ushort4*)&Bs[sec][nn][k4] = v;
    }
    // stage A with fp32->bf16: 128*32 float4 chunks / 512 = 8 each
#pragma unroll
    for (int t = 0; t < 8; t++) {
        int c = tid + t * 512;
        int r = c >> 5;
        int k4 = (c & 31) << 2;
        int gr = row0 + r;
        float4 v = (gr < n) ? *(const float4*)(H + (size_t)gr * DIM + k4)
                            : make_float4(0.f, 0.f, 0.f, 0.f);
        ushort4 b;
        b.x = f2b(v.x); b.y = f2b(v.y); b.z = f2b(v.z); b.w = f2b(v.w);
        *(ushort4*)&As[r][k4] = b;
    }
    __syncthreads();

    int w = tid >> 6, l = tid & 63;
    int lr = l & 15;               // row-in-16 (A) / col-in-16 (B)
    int lk = (l >> 4) << 3;        // k sub-offset (8 bf16)
    int arow = w * 16 + lr;

    for (int sec = 0; sec < 3; sec++) {
        floatx4 acc[8];
#pragma unroll
        for (int nr = 0; nr < 8; nr++) acc[nr] = (floatx4){0.f, 0.f, 0.f, 0.f};
#pragma unroll
        for (int ks = 0; ks < 4; ks++) {
            short8 a = *(const short8*)&As[arow][ks * 32 + lk];
#pragma unroll
            for (int nr = 0; nr < 8; nr++) {
                short8 b = *(const short8*)&Bs[sec][nr * 16 + lr][ks * 32 + lk];
                acc[nr] = __builtin_amdgcn_mfma_f32_16x16x32_bf16(a, b, acc[nr], 0, 0, 0);
            }
        }
        const float* bias = (sec == 0) ? bl : (sec == 1) ? br : bres;
        int rbase = row0 + w * 16 + ((l >> 4) << 2);
#pragma unroll
        for (int nr = 0; nr < 8; nr++) {
            int col = nr * 16 + lr;
            float bv = bias[col];
#pragma unroll
            for (int r = 0; r < 4; r++) {
                int gr = rbase + r;
                if (gr >= n) continue;
                float val = acc[nr][r] + bv;
                if (sec == 0)      XLb[(size_t)gr * DIM + col] = f2b(val);
                else if (sec == 1) XR[(size_t)gr * DIM + col] = val;
                else               RES[(size_t)gr * DIM + col] = val;
            }
        }
    }
}

// ---------------- aggregation: 1 wave/node, two 32-lane subgroups over alternating edges ----------------
__global__ __launch_bounds__(256) void k_aggr(
    const unsigned short* __restrict__ XLb, const float* __restrict__ XR,
    const float* __restrict__ RES, const float* __restrict__ att,
    const float* __restrict__ bias, const int* __restrict__ rowptr,
    const int* __restrict__ srt, float* __restrict__ out, int n)
{
    int wave = threadIdx.x >> 6;
    int lane = threadIdx.x & 63;
    int node = blockIdx.x * 4 + wave;
    if (node >= n) return;
    int half = lane >> 5, sl = lane & 31;
    int d0 = sl << 2;

    float4 a4 = *(const float4*)(att + d0);
    float4 x4 = *(const float4*)(XR + (size_t)node * DIM + d0);
    int beg = rowptr[node], end = rowptr[node + 1];

    float m = -INFINITY, den = 0.f;
    float ax = 0.f, ay = 0.f, az = 0.f, aw = 0.f;

    int j = beg + half;
    // 2 edges per iteration per half (4 in flight per wave)
    while (j + 2 < end) {
        int s0 = srt[j], s1 = srt[j + 2];
        ushort4 u0 = *(const ushort4*)(XLb + (size_t)s0 * DIM + d0);
        ushort4 u1 = *(const ushort4*)(XLb + (size_t)s1 * DIM + d0);
        float v0x = b2f(u0.x), v0y = b2f(u0.y), v0z = b2f(u0.z), v0w = b2f(u0.w);
        float v1x = b2f(u1.x), v1y = b2f(u1.y), v1z = b2f(u1.z), v1w = b2f(u1.w);
        float t, p0, p1;
        t = v0x + x4.x; p0  = (t > 0.f ? t : NEG_SLOPE * t) * a4.x;
        t = v0y + x4.y; p0 += (t > 0.f ? t : NEG_SLOPE * t) * a4.y;
        t = v0z + x4.z; p0 += (t > 0.f ? t : NEG_SLOPE * t) * a4.z;
        t = v0w + x4.w; p0 += (t > 0.f ? t : NEG_SLOPE * t) * a4.w;
        t = v1x + x4.x; p1  = (t > 0.f ? t : NEG_SLOPE * t) * a4.x;
        t = v1y + x4.y; p1 += (t > 0.f ? t : NEG_SLOPE * t) * a4.y;
        t = v1z + x4.z; p1 += (t > 0.f ? t : NEG_SLOPE * t) * a4.z;
        t = v1w + x4.w; p1 += (t > 0.f ? t : NEG_SLOPE * t) * a4.w;
#pragma unroll
        for (int off = 16; off >= 1; off >>= 1) {
            p0 += __shfl_xor(p0, off);
            p1 += __shfl_xor(p1, off);
        }
        float mn = fmaxf(m, fmaxf(p0, p1));
        float c  = __expf(m - mn);
        float w0 = __expf(p0 - mn);
        float w1 = __expf(p1 - mn);
        ax = ax * c + w0 * v0x + w1 * v1x;
        ay = ay * c + w0 * v0y + w1 * v1y;
        az = az * c + w0 * v0z + w1 * v1z;
        aw = aw * c + w0 * v0w + w1 * v1w;
        den = den * c + w0 + w1;
        m = mn;
        j += 4;
    }
    if (j < end) {
        int s0 = srt[j];
        ushort4 u0 = *(const ushort4*)(XLb + (size_t)s0 * DIM + d0);
        float v0x = b2f(u0.x), v0y = b2f(u0.y), v0z = b2f(u0.z), v0w = b2f(u0.w);
        float t, p0;
        t = v0x + x4.x; p0  = (t > 0.f ? t : NEG_SLOPE * t) * a4.x;
        t = v0y + x4.y; p0 += (t > 0.f ? t : NEG_SLOPE * t) * a4.y;
        t = v0z + x4.z; p0 += (t > 0.f ? t : NEG_SLOPE * t) * a4.z;
        t = v0w + x4.w; p0 += (t > 0.f ? t : NEG_SLOPE * t) * a4.w;
#pragma unroll
        for (int off = 16; off >= 1; off >>= 1) p0 += __shfl_xor(p0, off);
        float mn = fmaxf(m, p0);
        float c  = __expf(m - mn);
        float w0 = __expf(p0 - mn);
        ax = ax * c + w0 * v0x;
        ay = ay * c + w0 * v0y;
        az = az * c + w0 * v0z;
        aw = aw * c + w0 * v0w;
        den = den * c + w0;
        m = mn;
    }

    // merge the two half-wave online softmaxes
    float om   = __shfl_xor(m, 32);
    float oden = __shfl_xor(den, 32);
    float ox = __shfl_xor(ax, 32), oy = __shfl_xor(ay, 32);
    float oz = __shfl_xor(az, 32), ow = __shfl_xor(aw, 32);
    float M  = fmaxf(m, om);
    float se = __expf(m - M), so = __expf(om - M);
    float D  = den * se + oden * so + 1e-16f;
    float inv = 1.f / D;

    float4 r4 = *(const float4*)(RES + (size_t)node * DIM + d0);
    float4 b4 = *(const float4*)(bias + d0);
    float4 o;
    o.x = fmaxf((ax * se + ox * so) * inv + b4.x + r4.x, 0.f);
    o.y = fmaxf((ay * se + oy * so) * inv + b4.y + r4.y, 0.f);
    o.z = fmaxf((az * se + oz * so) * inv + b4.z + r4.z, 0.f);
    o.w = fmaxf((aw * se + ow * so) * inv + b4.w + r4.w, 0.f);
    if (half == 0) *(float4*)(out + (size_t)node * DIM + d0) = o;
}

extern "C" void kernel_launch(void* const* d_in, const int* in_sizes, int n_in,
                              void* d_out, int out_size, void* d_ws, size_t ws_size,
                              hipStream_t stream) {
    const float* x    = (const float*)d_in[0];
    const int*   ei   = (const int*)d_in[1];
    const float* Wl   = (const float*)d_in[2];
    const float* bl   = (const float*)d_in[3];
    const float* Wr   = (const float*)d_in[4];
    const float* br   = (const float*)d_in[5];
    const float* att  = (const float*)d_in[6];
    const float* bias = (const float*)d_in[7];
    const float* Wres = (const float*)d_in[8];
    const float* bres = (const float*)d_in[9];

    int n = in_sizes[0] / DIM;
    int E = in_sizes[1] / 2;
    const int* srcIdx = ei;
    const int* dstIdx = ei + E;

    // workspace layout
    float* xr   = (float*)d_ws;
    float* resb = xr + (size_t)n * DIM;
    float* hbuf = resb + (size_t)n * DIM;
    unsigned short* xlb = (unsigned short*)(hbuf + (size_t)n * DIM);
    unsigned short* wt  = xlb + (size_t)n * DIM;
    int* rowptr = (int*)(wt + 2 * 3 * DIM * DIM);
    int* tmpc   = rowptr + (n + 1);
    int* srt    = tmpc + n;
    int* bsum   = srt + (E + n);

    int nb1 = (n + 255) / 256;

    k_init_counts<<<(n + 255) / 256, 256, 0, stream>>>(tmpc, n);
    k_count<<<(E + 255) / 256, 256, 0, stream>>>(dstIdx, E, tmpc);
    k_scan1<<<nb1, 256, 0, stream>>>(tmpc, n, rowptr, bsum);
    k_scan2<<<1, 256, 0, stream>>>(bsum, nb1);
    k_scan3<<<nb1, 256, 0, stream>>>(rowptr, bsum, n, tmpc);
    k_scatter<<<(E + n + 255) / 256, 256, 0, stream>>>(srcIdx, dstIdx, E, n, tmpc, srt);
    k_wconv<<<(2 * 3 * DIM * DIM + 255) / 256, 256, 0, stream>>>(Wl, Wr, Wres, wt);

    const float* h = x;
    for (int l = 0; l < 2; l++) {
        float* ho = (l == 0) ? hbuf : (float*)d_out;
        int gx = (n + 127) / 128;
        k_gemm<<<gx, 512, 0, stream>>>(h, wt + (size_t)l * 3 * DIM * DIM,
                                       bl + (size_t)l * DIM, br + (size_t)l * DIM, bres,
                                       xlb, xr, resb, n);
        k_aggr<<<(n + 3) / 4, 256, 0, stream>>>(xlb, xr, resb, att + (size_t)l * DIM,
                                                bias + (size_t)l * DIM, rowptr, srt, ho, n);
        h = ho;
    }
}

// Round 3
// 218.685 us; speedup vs baseline: 1.9743x; 1.1833x over previous
//
#include <hip/hip_runtime.h>
#include <math.h>

// GATv2 x2 layers, N=50000, E=600000, D=128.
//  CSR over dst -> per layer: register-resident-W MFMA GEMM (no LDS, no barriers)
//  from pre-fragmented bf16 operands, then per-node online-softmax aggregation.

#define DIM 128
#define NEG_SLOPE 0.2f
#define TPW 4   // row-tiles per wave in k_gemm

typedef __attribute__((ext_vector_type(8))) short short8;
typedef __attribute__((ext_vector_type(4))) float floatx4;

static __device__ __forceinline__ unsigned short f2b(float f) {
    unsigned u = __float_as_uint(f);
    unsigned r = (u + 0x7FFFu + ((u >> 16) & 1u)) >> 16;   // RNE
    return (unsigned short)r;
}
static __device__ __forceinline__ float b2f(unsigned short h) {
    return __uint_as_float(((unsigned)h) << 16);
}

// ---------------- CSR build ----------------
__global__ void k_init_counts(int* __restrict__ counts, int n) {
    int i = blockIdx.x * blockDim.x + threadIdx.x;
    if (i < n) counts[i] = 1;  // self loop
}

__global__ void k_count(const int* __restrict__ dst, int E, int* __restrict__ counts) {
    int k = blockIdx.x * blockDim.x + threadIdx.x;
    if (k < E) atomicAdd(&counts[dst[k]], 1);
}

__global__ void k_scan1(const int* __restrict__ counts, int n,
                        int* __restrict__ rowptr, int* __restrict__ bsum) {
    __shared__ int s[256];
    int tid = threadIdx.x;
    int i = blockIdx.x * 256 + tid;
    int v = (i < n) ? counts[i] : 0;
    s[tid] = v;
    __syncthreads();
    for (int off = 1; off < 256; off <<= 1) {
        int t = (tid >= off) ? s[tid - off] : 0;
        __syncthreads();
        s[tid] += t;
        __syncthreads();
    }
    if (i < n) rowptr[i + 1] = s[tid];
    if (tid == 255) bsum[blockIdx.x] = s[255];
}

__global__ void k_scan2(int* __restrict__ bsum, int nb) {
    __shared__ int s[256];
    int tid = threadIdx.x;
    int v = (tid < nb) ? bsum[tid] : 0;
    s[tid] = v;
    __syncthreads();
    for (int off = 1; off < 256; off <<= 1) {
        int t = (tid >= off) ? s[tid - off] : 0;
        __syncthreads();
        s[tid] += t;
        __syncthreads();
    }
    if (tid < nb) bsum[tid] = s[tid];
}

__global__ void k_scan3(int* __restrict__ rowptr, const int* __restrict__ bsum,
                        int n, int* __restrict__ counts_to_cursors) {
    int i = blockIdx.x * 256 + threadIdx.x;
    if (i < n) {
        int add = (blockIdx.x > 0) ? bsum[blockIdx.x - 1] : 0;
        int cnt = counts_to_cursors[i];
        int v = rowptr[i + 1] + add;
        rowptr[i + 1] = v;
        counts_to_cursors[i] = v - cnt;  // cursor = exclusive prefix
    }
    if (i == 0) rowptr[0] = 0;
}

__global__ void k_scatter(const int* __restrict__ src, const int* __restrict__ dst,
                          int E, int n, int* __restrict__ cur, int* __restrict__ srt) {
    int k = blockIdx.x * blockDim.x + threadIdx.x;
    int tot = E + n;
    if (k >= tot) return;
    int s, d;
    if (k < E) { s = src[k]; d = dst[k]; }
    else       { s = k - E;  d = s; }
    int p = atomicAdd(&cur[d], 1);
    srt[p] = s;
}

// ---------------- W fragmentization ----------------
// wfrag[l][sec][ks][nr][lane][j] = bf16( W[ks*32+(lane>>4)*8+j][nr*16+(lane&15)] )
__global__ void k_wfrag(const float* __restrict__ Wl, const float* __restrict__ Wr,
                        const float* __restrict__ Wres, unsigned short* __restrict__ out) {
    int idx = blockIdx.x * blockDim.x + threadIdx.x;
    if (idx >= 2 * 3 * 4 * 8 * 64) return;
    int lane = idx & 63;
    int nr   = (idx >> 6) & 7;
    int ks   = (idx >> 9) & 3;
    int v    = idx >> 11;             // l*3+sec
    int sec = v % 3, l = v / 3;
    const float* W = (sec == 0) ? (Wl + l * DIM * DIM)
                   : (sec == 1) ? (Wr + l * DIM * DIM) : Wres;
    int nn = nr * 16 + (lane & 15);
    int k0 = ks * 32 + ((lane >> 4) << 3);
    ushort4 a, b;
    a.x = f2b(W[(k0 + 0) * DIM + nn]); a.y = f2b(W[(k0 + 1) * DIM + nn]);
    a.z = f2b(W[(k0 + 2) * DIM + nn]); a.w = f2b(W[(k0 + 3) * DIM + nn]);
    b.x = f2b(W[(k0 + 4) * DIM + nn]); b.y = f2b(W[(k0 + 5) * DIM + nn]);
    b.z = f2b(W[(k0 + 6) * DIM + nn]); b.w = f2b(W[(k0 + 7) * DIM + nn]);
    *(ushort4*)(out + (size_t)idx * 8) = a;
    *(ushort4*)(out + (size_t)idx * 8 + 4) = b;
}

// ---------------- H fragmentization (layer 0 input) ----------------
// hfrag[tile][ks][lane][j] = bf16( h[tile*16+(lane&15)][ks*32+(lane>>4)*8+j] )
__global__ void k_hfrag(const float* __restrict__ h, unsigned short* __restrict__ out,
                        int n, int ntiles) {
    int idx = blockIdx.x * blockDim.x + threadIdx.x;
    if (idx >= ntiles * 256) return;
    int lane = idx & 63;
    int ks   = (idx >> 6) & 3;
    int tile = idx >> 8;
    int row  = tile * 16 + (lane & 15);
    int col0 = ks * 32 + ((lane >> 4) << 3);
    ushort4 a = {0, 0, 0, 0}, b = {0, 0, 0, 0};
    if (row < n) {
        float4 v0 = *(const float4*)(h + (size_t)row * DIM + col0);
        float4 v1 = *(const float4*)(h + (size_t)row * DIM + col0 + 4);
        a.x = f2b(v0.x); a.y = f2b(v0.y); a.z = f2b(v0.z); a.w = f2b(v0.w);
        b.x = f2b(v1.x); b.y = f2b(v1.y); b.z = f2b(v1.z); b.w = f2b(v1.w);
    }
    *(ushort4*)(out + (size_t)idx * 8) = a;
    *(ushort4*)(out + (size_t)idx * 8 + 4) = b;
}

// ---------------- register-resident-W MFMA GEMM ----------------
// grid (gx, 3); block 256 (4 waves). Wave holds section W in 32 short8 regs,
// processes TPW consecutive 16-row tiles. No LDS, no barriers.
// mfma(wfrag, hfrag, acc): acc[nr] reg r = C[row=t*16+(l&15)][col=nr*16+(l>>4)*4+r]
__global__ __launch_bounds__(256, 2) void k_gemm(
    const unsigned short* __restrict__ hfrag, const unsigned short* __restrict__ wfrag,
    const float* __restrict__ bl, const float* __restrict__ br, const float* __restrict__ bres,
    unsigned short* __restrict__ XLb, float* __restrict__ XR, float* __restrict__ RES,
    int ntiles)
{
    int sec  = blockIdx.y;
    int lane = threadIdx.x & 63;
    int w    = threadIdx.x >> 6;

    const unsigned short* wbase = wfrag + (size_t)sec * (4 * 8 * 64 * 8);
    short8 bf[4][8];
#pragma unroll
    for (int ks = 0; ks < 4; ks++)
#pragma unroll
        for (int nr = 0; nr < 8; nr++)
            bf[ks][nr] = *(const short8*)(wbase + (((ks * 8 + nr) * 64 + lane) << 3));

    const float* bias = (sec == 0) ? bl : (sec == 1) ? br : bres;
    int colb = (lane >> 4) << 2;
    float4 bv[8];
#pragma unroll
    for (int nr = 0; nr < 8; nr++) bv[nr] = *(const float4*)(bias + nr * 16 + colb);

    int wid = blockIdx.x * 4 + w;
#pragma unroll
    for (int i = 0; i < TPW; i++) {
        int t = wid * TPW + i;
        if (t >= ntiles) break;
        short8 a[4];
#pragma unroll
        for (int ks = 0; ks < 4; ks++)
            a[ks] = *(const short8*)(hfrag + (((t * 4 + ks) * 64 + lane) << 3));
        floatx4 acc[8];
#pragma unroll
        for (int nr = 0; nr < 8; nr++) acc[nr] = (floatx4){0.f, 0.f, 0.f, 0.f};
#pragma unroll
        for (int ks = 0; ks < 4; ks++)
#pragma unroll
            for (int nr = 0; nr < 8; nr++)
                acc[nr] = __builtin_amdgcn_mfma_f32_16x16x32_bf16(bf[ks][nr], a[ks], acc[nr], 0, 0, 0);

        int row = t * 16 + (lane & 15);
        size_t rb = (size_t)row * DIM;
#pragma unroll
        for (int nr = 0; nr < 8; nr++) {
            float4 o;
            o.x = acc[nr][0] + bv[nr].x;
            o.y = acc[nr][1] + bv[nr].y;
            o.z = acc[nr][2] + bv[nr].z;
            o.w = acc[nr][3] + bv[nr].w;
            int col = nr * 16 + colb;
            if (sec == 0) {
                ushort4 u;
                u.x = f2b(o.x); u.y = f2b(o.y); u.z = f2b(o.z); u.w = f2b(o.w);
                *(ushort4*)(XLb + rb + col) = u;
            } else if (sec == 1) {
                *(float4*)(XR + rb + col) = o;
            } else {
                *(float4*)(RES + rb + col) = o;
            }
        }
    }
}

// ---------------- aggregation ----------------
// 1 wave/node, two 32-lane subgroups over contiguous halves, 4 edges in flight each.
// Epilogue: writeFrag=1 -> write bf16 hfrag (next layer GEMM input); else fp32 row-major out.
__global__ __launch_bounds__(256) void k_aggr(
    const unsigned short* __restrict__ XLb, const float* __restrict__ XR,
    const float* __restrict__ RES, const float* __restrict__ att,
    const float* __restrict__ bias, const int* __restrict__ rowptr,
    const int* __restrict__ srt, float* __restrict__ outF,
    unsigned short* __restrict__ fragOut, int writeFrag, int n)
{
    int wave = threadIdx.x >> 6;
    int lane = threadIdx.x & 63;
    int node = blockIdx.x * 4 + wave;
    if (node >= n) return;
    int half = lane >> 5, sl = lane & 31;
    int d0 = sl << 2;

    float4 a4 = *(const float4*)(att + d0);
    float4 x4 = *(const float4*)(XR + (size_t)node * DIM + d0);
    int beg = rowptr[node], end = rowptr[node + 1];
    int len = end - beg;
    int hl = (len + 1) >> 1;
    int sb = beg + half * hl;
    int se = half ? end : (beg + hl);

    float m = -INFINITY, den = 0.f;
    float ax = 0.f, ay = 0.f, az = 0.f, aw = 0.f;

    int j = sb;
    for (; j + 4 <= se; j += 4) {
        int s0 = srt[j], s1 = srt[j + 1], s2 = srt[j + 2], s3 = srt[j + 3];
        ushort4 u0 = *(const ushort4*)(XLb + (size_t)s0 * DIM + d0);
        ushort4 u1 = *(const ushort4*)(XLb + (size_t)s1 * DIM + d0);
        ushort4 u2 = *(const ushort4*)(XLb + (size_t)s2 * DIM + d0);
        ushort4 u3 = *(const ushort4*)(XLb + (size_t)s3 * DIM + d0);
        float v0x = b2f(u0.x), v0y = b2f(u0.y), v0z = b2f(u0.z), v0w = b2f(u0.w);
        float v1x = b2f(u1.x), v1y = b2f(u1.y), v1z = b2f(u1.z), v1w = b2f(u1.w);
        float v2x = b2f(u2.x), v2y = b2f(u2.y), v2z = b2f(u2.z), v2w = b2f(u2.w);
        float v3x = b2f(u3.x), v3y = b2f(u3.y), v3z = b2f(u3.z), v3w = b2f(u3.w);
        float t, p0, p1, p2, p3;
        t = v0x + x4.x; p0  = fmaxf(t, NEG_SLOPE * t) * a4.x;
        t = v0y + x4.y; p0 += fmaxf(t, NEG_SLOPE * t) * a4.y;
        t = v0z + x4.z; p0 += fmaxf(t, NEG_SLOPE * t) * a4.z;
        t = v0w + x4.w; p0 += fmaxf(t, NEG_SLOPE * t) * a4.w;
        t = v1x + x4.x; p1  = fmaxf(t, NEG_SLOPE * t) * a4.x;
        t = v1y + x4.y; p1 += fmaxf(t, NEG_SLOPE * t) * a4.y;
        t = v1z + x4.z; p1 += fmaxf(t, NEG_SLOPE * t) * a4.z;
        t = v1w + x4.w; p1 += fmaxf(t, NEG_SLOPE * t) * a4.w;
        t = v2x + x4.x; p2  = fmaxf(t, NEG_SLOPE * t) * a4.x;
        t = v2y + x4.y; p2 += fmaxf(t, NEG_SLOPE * t) * a4.y;
        t = v2z + x4.z; p2 += fmaxf(t, NEG_SLOPE * t) * a4.z;
        t = v2w + x4.w; p2 += fmaxf(t, NEG_SLOPE * t) * a4.w;
        t = v3x + x4.x; p3  = fmaxf(t, NEG_SLOPE * t) * a4.x;
        t = v3y + x4.y; p3 += fmaxf(t, NEG_SLOPE * t) * a4.y;
        t = v3z + x4.z; p3 += fmaxf(t, NEG_SLOPE * t) * a4.z;
        t = v3w + x4.w; p3 += fmaxf(t, NEG_SLOPE * t) * a4.w;
#pragma unroll
        for (int off = 16; off >= 1; off >>= 1) {
            p0 += __shfl_xor(p0, off);
            p1 += __shfl_xor(p1, off);
            p2 += __shfl_xor(p2, off);
            p3 += __shfl_xor(p3, off);
        }
        float pm = fmaxf(fmaxf(p0, p1), fmaxf(p2, p3));
        float mn = fmaxf(m, pm);
        float c  = __expf(m - mn);
        float w0 = __expf(p0 - mn), w1 = __expf(p1 - mn);
        float w2 = __expf(p2 - mn), w3 = __expf(p3 - mn);
        ax = ax * c + w0 * v0x + w1 * v1x + w2 * v2x + w3 * v3x;
        ay = ay * c + w0 * v0y + w1 * v1y + w2 * v2y + w3 * v3y;
        az = az * c + w0 * v0z + w1 * v1z + w2 * v2z + w3 * v3z;
        aw = aw * c + w0 * v0w + w1 * v1w + w2 * v2w + w3 * v3w;
        den = den * c + w0 + w1 + w2 + w3;
        m = mn;
    }
    for (; j < se; j++) {
        int s0 = srt[j];
        ushort4 u0 = *(const ushort4*)(XLb + (size_t)s0 * DIM + d0);
        float v0x = b2f(u0.x), v0y = b2f(u0.y), v0z = b2f(u0.z), v0w = b2f(u0.w);
        float t, p0;
        t = v0x + x4.x; p0  = fmaxf(t, NEG_SLOPE * t) * a4.x;
        t = v0y + x4.y; p0 += fmaxf(t, NEG_SLOPE * t) * a4.y;
        t = v0z + x4.z; p0 += fmaxf(t, NEG_SLOPE * t) * a4.z;
        t = v0w + x4.w; p0 += fmaxf(t, NEG_SLOPE * t) * a4.w;
#pragma unroll
        for (int off = 16; off >= 1; off >>= 1) p0 += __shfl_xor(p0, off);
        float mn = fmaxf(m, p0);
        float c  = __expf(m - mn);
        float w0 = __expf(p0 - mn);
        ax = ax * c + w0 * v0x;
        ay = ay * c + w0 * v0y;
        az = az * c + w0 * v0z;
        aw = aw * c + w0 * v0w;
        den = den * c + w0;
        m = mn;
    }

    // merge the two half-wave online softmaxes
    float om   = __shfl_xor(m, 32);
    float oden = __shfl_xor(den, 32);
    float ox = __shfl_xor(ax, 32), oy = __shfl_xor(ay, 32);
    float oz = __shfl_xor(az, 32), ow = __shfl_xor(aw, 32);
    float M  = fmaxf(m, om);
    float se_ = __expf(m - M), so = __expf(om - M);
    float D  = den * se_ + oden * so + 1e-16f;
    float inv = 1.f / D;

    float4 r4 = *(const float4*)(RES + (size_t)node * DIM + d0);
    float4 b4 = *(const float4*)(bias + d0);
    float4 o;
    o.x = fmaxf((ax * se_ + ox * so) * inv + b4.x + r4.x, 0.f);
    o.y = fmaxf((ay * se_ + oy * so) * inv + b4.y + r4.y, 0.f);
    o.z = fmaxf((az * se_ + oz * so) * inv + b4.z + r4.z, 0.f);
    o.w = fmaxf((aw * se_ + ow * so) * inv + b4.w + r4.w, 0.f);

    if (half == 0) {
        if (writeFrag) {
            int tile = node >> 4;
            int ks = sl >> 3;
            int li = (node & 15) + (((sl >> 1) & 3) << 4);
            int j0 = (sl & 1) << 2;
            ushort4 u;
            u.x = f2b(o.x); u.y = f2b(o.y); u.z = f2b(o.z); u.w = f2b(o.w);
            *(ushort4*)(fragOut + ((size_t)((tile * 4 + ks) * 64 + li) << 3) + j0) = u;
        } else {
            *(float4*)(outF + (size_t)node * DIM + d0) = o;
        }
    }
}

extern "C" void kernel_launch(void* const* d_in, const int* in_sizes, int n_in,
                              void* d_out, int out_size, void* d_ws, size_t ws_size,
                              hipStream_t stream) {
    const float* x    = (const float*)d_in[0];
    const int*   ei   = (const int*)d_in[1];
    const float* Wl   = (const float*)d_in[2];
    const float* bl   = (const float*)d_in[3];
    const float* Wr   = (const float*)d_in[4];
    const float* br   = (const float*)d_in[5];
    const float* att  = (const float*)d_in[6];
    const float* bias = (const float*)d_in[7];
    const float* Wres = (const float*)d_in[8];
    const float* bres = (const float*)d_in[9];

    int n = in_sizes[0] / DIM;
    int E = in_sizes[1] / 2;
    int ntiles = (n + 15) >> 4;
    const int* srcIdx = ei;
    const int* dstIdx = ei + E;

    // workspace layout
    float* xr   = (float*)d_ws;
    float* resb = xr + (size_t)n * DIM;
    unsigned short* xlb   = (unsigned short*)(resb + (size_t)n * DIM);
    unsigned short* hfrag = xlb + (size_t)n * DIM;
    unsigned short* wfrag = hfrag + (size_t)ntiles * 16 * DIM;
    int* rowptr = (int*)(wfrag + 2 * 3 * DIM * DIM);
    int* tmpc   = rowptr + (n + 1);
    int* srt    = tmpc + n;
    int* bsum   = srt + (E + n);

    int nb1 = (n + 255) / 256;

    k_init_counts<<<(n + 255) / 256, 256, 0, stream>>>(tmpc, n);
    k_count<<<(E + 255) / 256, 256, 0, stream>>>(dstIdx, E, tmpc);
    k_scan1<<<nb1, 256, 0, stream>>>(tmpc, n, rowptr, bsum);
    k_scan2<<<1, 256, 0, stream>>>(bsum, nb1);
    k_scan3<<<nb1, 256, 0, stream>>>(rowptr, bsum, n, tmpc);
    k_scatter<<<(E + n + 255) / 256, 256, 0, stream>>>(srcIdx, dstIdx, E, n, tmpc, srt);
    k_wfrag<<<(2 * 3 * 4 * 8 * 64 + 255) / 256, 256, 0, stream>>>(Wl, Wr, Wres, wfrag);
    k_hfrag<<<(ntiles * 256 + 255) / 256, 256, 0, stream>>>(x, hfrag, n, ntiles);

    int gx = (ntiles + 4 * TPW - 1) / (4 * TPW);
    for (int l = 0; l < 2; l++) {
        dim3 g(gx, 3);
        k_gemm<<<g, 256, 0, stream>>>(hfrag, wfrag + (size_t)l * 3 * 4 * 8 * 64 * 8,
                                      bl + (size_t)l * DIM, br + (size_t)l * DIM, bres,
                                      xlb, xr, resb, ntiles);
        k_aggr<<<(n + 3) / 4, 256, 0, stream>>>(xlb, xr, resb, att + (size_t)l * DIM,
                                                bias + (size_t)l * DIM, rowptr, srt,
                                                (float*)d_out, hfrag, (l == 0) ? 1 : 0, n);
    }
}